// Round 2
// baseline (20186.362 us; speedup 1.0000x reference)
//
#include <hip/hip_runtime.h>
#include <math.h>

// ConvS2S decoder forward, fp32 baseline (round 1: residual fused into
// attended_h GEMM epilogue; h buffer eliminated).
// Layout: all [B, *, TRG] activations kept time-major as rows r = b*TRG + t,
// i.e. [R=6400, C]. Conv(K=3,pad=1) = implicit GEMM over rows r-1,r,r+1
// (masked at t boundaries). GLU fused into conv epilogue (dual accumulators).
//
// B=64 SRC=100 EMB=512 HID=1024 TRG=100 OUT=10000 NL=8 K=3, R=6400.

#define SCALE_ 0.5477225575051661f   // sqrt(0.3)

// ---------------- small kernels ----------------

// m[b,s] = mean_e enc_conved[b,s,e]   (6400 rows x 512)
__global__ __launch_bounds__(256) void mean_kernel(const float* __restrict__ enc,
                                                   float* __restrict__ m) {
    int lane = threadIdx.x & 63;
    int row  = blockIdx.x * 4 + (threadIdx.x >> 6);   // 1600 blocks * 4 waves
    const float* p = enc + (size_t)row * 512;
    float s = 0.f;
    #pragma unroll
    for (int j = 0; j < 8; ++j) s += p[lane + j * 64];
    #pragma unroll
    for (int off = 32; off > 0; off >>= 1) s += __shfl_xor(s, off);
    if (lane == 0) m[row] = s * (1.f / 512.f);
}

// ht[b,t] = sum_s m[b,s]*tgt_W[t,s] + tgt_b[t]   (6400 outputs, K=100)
__global__ __launch_bounds__(256) void ht_kernel(const float* __restrict__ m,
                                                 const float* __restrict__ tgt_W,
                                                 const float* __restrict__ tgt_b,
                                                 float* __restrict__ ht) {
    int idx = blockIdx.x * 256 + threadIdx.x;   // < 6400
    int b = idx / 100, t = idx % 100;
    const float* mb = m + b * 100;
    const float* w  = tgt_W + t * 100;
    float s = tgt_b[t];
    for (int k = 0; k < 100; ++k) s += mb[k] * w[k];
    ht[idx] = s;
}

// tok[b,e] = sum_t ht[b,t]*tok_W[e,t] + tok_b[e]   (32768 outputs, K=100)
__global__ __launch_bounds__(256) void tok_kernel(const float* __restrict__ ht,
                                                  const float* __restrict__ tok_W,
                                                  const float* __restrict__ tok_b,
                                                  float* __restrict__ tok) {
    int idx = blockIdx.x * 256 + threadIdx.x;   // < 32768
    int b = idx >> 9, e = idx & 511;
    const float* h = ht + b * 100;
    const float* w = tok_W + e * 100;
    float s = tok_b[e];
    for (int k = 0; k < 100; ++k) s += h[k] * w[k];
    tok[idx] = s;
}

// embedded[r,e] = tok[b,e] + pos_emb[t,e]   (float4 over 3,276,800 elems)
__global__ __launch_bounds__(256) void embedded_kernel(const float* __restrict__ tok,
                                                       const float* __restrict__ pos,
                                                       float* __restrict__ emb) {
    int idx = blockIdx.x * 256 + threadIdx.x;   // < 819200 float4s
    int e4 = idx & 127;
    int r  = idx >> 7;
    int t = r % 100, b = r / 100;
    float4 tv = ((const float4*)tok)[b * 128 + e4];
    float4 pv = ((const float4*)pos)[t * 128 + e4];
    float4 o;
    o.x = tv.x + pv.x; o.y = tv.y + pv.y; o.z = tv.z + pv.z; o.w = tv.w + pv.w;
    ((float4*)emb)[idx] = o;
}

// row-wise softmax over s (100 elems), in place. one wave per row.
__global__ __launch_bounds__(256) void softmax_kernel(float* __restrict__ attn) {
    int lane = threadIdx.x & 63;
    int row  = blockIdx.x * 4 + (threadIdx.x >> 6);   // < 6400
    float* p = attn + (size_t)row * 100;
    float v0 = p[lane];
    float v1 = (lane + 64 < 100) ? p[lane + 64] : -1e30f;
    float mx = fmaxf(v0, v1);
    #pragma unroll
    for (int off = 32; off > 0; off >>= 1) mx = fmaxf(mx, __shfl_xor(mx, off));
    float e0 = expf(v0 - mx);
    float e1 = (lane + 64 < 100) ? expf(v1 - mx) : 0.f;
    float sm = e0 + e1;
    #pragma unroll
    for (int off = 32; off > 0; off >>= 1) sm += __shfl_xor(sm, off);
    float inv = 1.f / sm;
    p[lane] = e0 * inv;
    if (lane + 64 < 100) p[lane + 64] = e1 * inv;
}

__global__ __launch_bounds__(256) void copy4_kernel(const float* __restrict__ src,
                                                    float* __restrict__ dst) {
    int idx = blockIdx.x * 256 + threadIdx.x;   // < 160,000
    ((float4*)dst)[idx] = ((const float4*)src)[idx];
}

// ---------------- big GEMM: C[M,N] = A[M,K] * W[N,K]^T (+bias) (+epi) -----
// 128x128 block, 256 threads, 8x8 microtile as 2x2 quadrants of 4x4, BK=16.
// EPI 0: C = v                      (v = acc + bias)
// EPI 1: C = (v + add0) * scale                      (combined epilogue)
// EPI 2: C = ((v + add0) * scale + C_old) * scale    (attended_h + residual,
//                                                     in-place on C)
template <int EPI>
__global__ __launch_bounds__(256) void gemm128_kernel(
    const float* __restrict__ A, const float* __restrict__ W,
    const float* __restrict__ bias, const float* __restrict__ add0,
    float* __restrict__ C, int M, int N, int Kd, float scale) {
    __shared__ float As[16][132];
    __shared__ float Bs[16][132];
    const int m0 = blockIdx.y * 128, n0 = blockIdx.x * 128;
    const int tid = threadIdx.x;
    const int tx = tid & 15, ty = tid >> 4;
    float acc[2][2][4][4] = {};
    for (int k0 = 0; k0 < Kd; k0 += 16) {
        #pragma unroll
        for (int i = 0; i < 8; ++i) {
            int q = tid + i * 256;
            int row = q >> 4, kk = q & 15;
            int gr = m0 + row;
            As[kk][row] = (gr < M) ? A[(size_t)gr * Kd + k0 + kk] : 0.f;
            int gc = n0 + row;
            Bs[kk][row] = (gc < N) ? W[(size_t)gc * Kd + k0 + kk] : 0.f;
        }
        __syncthreads();
        #pragma unroll
        for (int kk = 0; kk < 16; ++kk) {
            float a[2][4], b[2][4];
            #pragma unroll
            for (int i = 0; i < 4; ++i) { a[0][i] = As[kk][ty * 4 + i]; a[1][i] = As[kk][64 + ty * 4 + i]; }
            #pragma unroll
            for (int j = 0; j < 4; ++j) { b[0][j] = Bs[kk][tx * 4 + j]; b[1][j] = Bs[kk][64 + tx * 4 + j]; }
            #pragma unroll
            for (int p = 0; p < 2; ++p)
                #pragma unroll
                for (int q2 = 0; q2 < 2; ++q2)
                    #pragma unroll
                    for (int i = 0; i < 4; ++i)
                        #pragma unroll
                        for (int j = 0; j < 4; ++j)
                            acc[p][q2][i][j] += a[p][i] * b[q2][j];
        }
        __syncthreads();
    }
    #pragma unroll
    for (int p = 0; p < 2; ++p) {
        #pragma unroll
        for (int i = 0; i < 4; ++i) {
            int gr = m0 + p * 64 + ty * 4 + i;
            if (gr >= M) continue;
            #pragma unroll
            for (int q2 = 0; q2 < 2; ++q2) {
                #pragma unroll
                for (int j = 0; j < 4; ++j) {
                    int gc = n0 + q2 * 64 + tx * 4 + j;
                    if (gc >= N) continue;
                    size_t idx = (size_t)gr * N + gc;
                    float v = acc[p][q2][i][j];
                    if (bias) v += bias[gc];
                    if (EPI == 1) v = (v + add0[idx]) * scale;
                    if (EPI == 2) v = ((v + add0[idx]) * scale + C[idx]) * scale;
                    C[idx] = v;
                }
            }
        }
    }
}

// ---------------- batched small GEMM (energy / attended) ------------------
// BT=true : C = A * Bm^T, Bm is [N,K]   (energy: combined x enc_conved)
// BT=false: C = A * Bm,   Bm is [K,N]   (attended: attn x enc_combined)
// 64x64 block, 4x4 microtile, BK=16, guards on M/N/K. blockIdx.z = batch.
template <bool BT>
__global__ __launch_bounds__(256) void bgemm_kernel(
    const float* __restrict__ A, const float* __restrict__ Bm,
    float* __restrict__ C, int M, int N, int Kd, int sA, int sB, int sC) {
    __shared__ float As[16][68];
    __shared__ float Bs[16][68];
    const float* Ab = A + (size_t)blockIdx.z * sA;
    const float* Bb = Bm + (size_t)blockIdx.z * sB;
    float* Cb = C + (size_t)blockIdx.z * sC;
    const int m0 = blockIdx.y * 64, n0 = blockIdx.x * 64;
    const int tid = threadIdx.x, tx = tid & 15, ty = tid >> 4;
    float acc[4][4] = {};
    for (int k0 = 0; k0 < Kd; k0 += 16) {
        #pragma unroll
        for (int i = 0; i < 4; ++i) {
            int q = tid + i * 256;
            int row = q >> 4, kk = q & 15;
            int gr = m0 + row, gk = k0 + kk;
            As[kk][row] = (gr < M && gk < Kd) ? Ab[(size_t)gr * Kd + gk] : 0.f;
            if (BT) {
                int gc = n0 + row;
                Bs[kk][row] = (gc < N && gk < Kd) ? Bb[(size_t)gc * Kd + gk] : 0.f;
            } else {
                int kk2 = q >> 6, col = q & 63;
                int gc = n0 + col, gk2 = k0 + kk2;
                Bs[kk2][col] = (gc < N && gk2 < Kd) ? Bb[(size_t)gk2 * N + gc] : 0.f;
            }
        }
        __syncthreads();
        #pragma unroll
        for (int kk = 0; kk < 16; ++kk) {
            float a[4], b[4];
            #pragma unroll
            for (int i = 0; i < 4; ++i) a[i] = As[kk][ty * 4 + i];
            #pragma unroll
            for (int j = 0; j < 4; ++j) b[j] = Bs[kk][tx * 4 + j];
            #pragma unroll
            for (int i = 0; i < 4; ++i)
                #pragma unroll
                for (int j = 0; j < 4; ++j) acc[i][j] += a[i] * b[j];
        }
        __syncthreads();
    }
    #pragma unroll
    for (int i = 0; i < 4; ++i) {
        int gr = m0 + ty * 4 + i;
        if (gr >= M) continue;
        #pragma unroll
        for (int j = 0; j < 4; ++j) {
            int gc = n0 + tx * 4 + j;
            if (gc >= N) continue;
            Cb[(size_t)gr * N + gc] = acc[i][j];
        }
    }
}

// ---------------- conv(K=3,pad=1) + bias + GLU, implicit GEMM -------------
// out_c[r,o] = a*sigmoid(g), a/g = bias + sum_{tap,h} W[o(+1024),h,tap]*X[r+tap-1,h]
// 128 rows x 64 o-cols per block; dual accumulators for GLU halves.
__global__ __launch_bounds__(256) void conv_glu_kernel(
    const float* __restrict__ X,    // [6400, 1024]
    const float* __restrict__ Wc,   // [2048, 1024, 3] (layer slice)
    const float* __restrict__ bc,   // [2048]
    float* __restrict__ C) {        // [6400, 1024]
    __shared__ float As[16][132];
    __shared__ float Ba[16][68];
    __shared__ float Bg[16][68];
    const int m0 = blockIdx.y * 128;
    const int n0 = blockIdx.x * 64;
    const int tid = threadIdx.x;
    const int tx = tid & 15, ty = tid >> 4;
    float acc_a[2][4][4] = {};
    float acc_g[2][4][4] = {};
    for (int tap = 0; tap < 3; ++tap) {
        const int dr = tap - 1;
        for (int k0 = 0; k0 < 1024; k0 += 16) {
            #pragma unroll
            for (int i = 0; i < 8; ++i) {
                int q = tid + i * 256;
                int row = q >> 4, kk = q & 15;
                int gr = m0 + row;
                int t = gr % 100;
                int ts = t + dr;
                float v = 0.f;
                if (ts >= 0 && ts < 100) v = X[(gr + dr) * 1024 + k0 + kk];
                As[kk][row] = v;
            }
            #pragma unroll
            for (int i = 0; i < 4; ++i) {
                int q = tid + i * 256;
                int col = q >> 4, kk = q & 15;
                int idx = ((n0 + col) * 1024 + k0 + kk) * 3 + tap;
                Ba[kk][col] = Wc[idx];
                Bg[kk][col] = Wc[idx + 3145728];   // +1024*1024*3 (gate half)
            }
            __syncthreads();
            #pragma unroll
            for (int kk = 0; kk < 16; ++kk) {
                float a0[4], a1[4], ba[4], bg[4];
                #pragma unroll
                for (int i = 0; i < 4; ++i) { a0[i] = As[kk][ty * 4 + i]; a1[i] = As[kk][64 + ty * 4 + i]; }
                #pragma unroll
                for (int j = 0; j < 4; ++j) { ba[j] = Ba[kk][tx * 4 + j]; bg[j] = Bg[kk][tx * 4 + j]; }
                #pragma unroll
                for (int i = 0; i < 4; ++i)
                    #pragma unroll
                    for (int j = 0; j < 4; ++j) {
                        acc_a[0][i][j] += a0[i] * ba[j];
                        acc_g[0][i][j] += a0[i] * bg[j];
                        acc_a[1][i][j] += a1[i] * ba[j];
                        acc_g[1][i][j] += a1[i] * bg[j];
                    }
            }
            __syncthreads();
        }
    }
    float bja[4], bjg[4];
    #pragma unroll
    for (int j = 0; j < 4; ++j) { int o = n0 + tx * 4 + j; bja[j] = bc[o]; bjg[j] = bc[o + 1024]; }
    #pragma unroll
    for (int p = 0; p < 2; ++p)
        #pragma unroll
        for (int i = 0; i < 4; ++i) {
            int gr = m0 + p * 64 + ty * 4 + i;
            #pragma unroll
            for (int j = 0; j < 4; ++j) {
                float av = acc_a[p][i][j] + bja[j];
                float gv = acc_g[p][i][j] + bjg[j];
                float s = 1.f / (1.f + expf(-gv));
                C[(size_t)gr * 1024 + n0 + tx * 4 + j] = av * s;
            }
        }
}

// ---------------- launch ----------------

extern "C" void kernel_launch(void* const* d_in, const int* in_sizes, int n_in,
                              void* d_out, int out_size, void* d_ws, size_t ws_size,
                              hipStream_t stream) {
    const float* enc_conved   = (const float*)d_in[0];
    const float* enc_combined = (const float*)d_in[1];
    const float* tok_W  = (const float*)d_in[2];
    const float* tok_b  = (const float*)d_in[3];
    const float* pos    = (const float*)d_in[4];
    const float* tgt_W  = (const float*)d_in[5];
    const float* tgt_b  = (const float*)d_in[6];
    const float* e2h_W  = (const float*)d_in[7];
    const float* e2h_b  = (const float*)d_in[8];
    const float* h2e_W  = (const float*)d_in[9];
    const float* h2e_b  = (const float*)d_in[10];
    const float* ah2e_W = (const float*)d_in[11];
    const float* ah2e_b = (const float*)d_in[12];
    const float* ae2h_W = (const float*)d_in[13];
    const float* ae2h_b = (const float*)d_in[14];
    const float* fc_W   = (const float*)d_in[15];
    const float* fc_b   = (const float*)d_in[16];
    const float* conv_W = (const float*)d_in[17];
    const float* conv_b = (const float*)d_in[18];
    float* out = (float*)d_out;

    // workspace (floats): ~81 MB total
    float* ws   = (float*)d_ws;
    float* emb  = ws;                  // 3,276,800  [6400,512] embedded
    float* x    = emb  + 3276800;      // 6,553,600  [6400,1024] conv_input / residual
    float* c    = x    + 6553600;      // 6,553,600  [6400,1024] GLU out
    float* e    = c    + 6553600;      // 3,276,800  [6400,512] emb-dim scratch
    float* attn = e    + 3276800;      //   640,000  [6400,100]
    float* mbuf = attn + 640000;       //     6,400
    float* htb  = mbuf + 6400;         //     6,400
    float* tokb = htb  + 6400;         //    32,768

    mean_kernel<<<1600, 256, 0, stream>>>(enc_conved, mbuf);
    ht_kernel<<<25, 256, 0, stream>>>(mbuf, tgt_W, tgt_b, htb);
    tok_kernel<<<128, 256, 0, stream>>>(htb, tok_W, tok_b, tokb);
    embedded_kernel<<<3200, 256, 0, stream>>>(tokb, pos, emb);
    // conv_input = embedded @ e2h_W^T + b   [6400,1024]
    gemm128_kernel<0><<<dim3(8, 50), 256, 0, stream>>>(emb, e2h_W, e2h_b, nullptr, x,
                                                       6400, 1024, 512, 0.f);
    for (int i = 0; i < 8; ++i) {
        conv_glu_kernel<<<dim3(16, 50), 256, 0, stream>>>(
            x, conv_W + (size_t)i * 6291456, conv_b + i * 2048, c);
        // combined = (c @ ah2e_W^T + b + embedded) * SCALE   [6400,512]
        gemm128_kernel<1><<<dim3(4, 50), 256, 0, stream>>>(c, ah2e_W, ah2e_b, emb, e,
                                                           6400, 512, 1024, SCALE_);
        // energy[b] = combined[b] @ enc_conved[b]^T   [100,100] x64
        bgemm_kernel<true><<<dim3(2, 2, 64), 256, 0, stream>>>(e, enc_conved, attn,
                                                               100, 100, 512,
                                                               51200, 51200, 10000);
        softmax_kernel<<<1600, 256, 0, stream>>>(attn);
        // attended[b] = attn[b] @ enc_combined[b]   [100,512] x64
        bgemm_kernel<false><<<dim3(8, 2, 64), 256, 0, stream>>>(attn, enc_combined, e,
                                                                100, 512, 100,
                                                                10000, 51200, 51200);
        // x = ((c + (e @ ae2h_W^T + b)) * SCALE + x) * SCALE   (fused residual)
        gemm128_kernel<2><<<dim3(8, 50), 256, 0, stream>>>(e, ae2h_W, ae2h_b, c, x,
                                                           6400, 1024, 512, SCALE_);
    }
    // conved_e = x @ h2e_W^T + b   [6400,512]
    gemm128_kernel<0><<<dim3(4, 50), 256, 0, stream>>>(x, h2e_W, h2e_b, nullptr, e,
                                                       6400, 512, 1024, 0.f);
    // output = conved_e @ fc_W^T + b   [6400,10000]
    gemm128_kernel<0><<<dim3(79, 50), 256, 0, stream>>>(e, fc_W, fc_b, nullptr, out,
                                                        6400, 10000, 512, 0.f);
    // attention output tail (last layer's softmax)
    copy4_kernel<<<625, 256, 0, stream>>>(attn, out + 64000000);
}